// Round 6
// baseline (540.486 us; speedup 1.0000x reference)
//
#include <hip/hip_runtime.h>
#include <hip/hip_bf16.h>

typedef unsigned short u16;
typedef short bf16x8 __attribute__((ext_vector_type(8)));
typedef float f32x4 __attribute__((ext_vector_type(4)));
typedef unsigned short u16x8 __attribute__((ext_vector_type(8)));

#define GLL16(gp, lp) __builtin_amdgcn_global_load_lds( \
    (__attribute__((address_space(1))) const unsigned int*)(gp), \
    (__attribute__((address_space(3))) unsigned int*)(lp), 16, 0, 0)

// HW RNE f32->bf16 (compiler pairs these into v_cvt_pk_bf16_f32)
static __device__ __forceinline__ u16 f2bf(float f){
  return __builtin_bit_cast(u16, __float2bfloat16(f));
}

// ---------------- transpose + convert: dst[b][c][r] = bf16(src[b][r][c]), r zero-padded to Rpad
__global__ void transpose_f32(const float* __restrict__ src, u16* __restrict__ dst,
                              int R, int C, int Rpad, long sB, long dB){
  __shared__ u16 tile[32][33];
  const int b = blockIdx.z;
  src += (long)b*sB; dst += (long)b*dB;
  const int r0 = blockIdx.x*32, c0 = blockIdx.y*32;
  const int j = threadIdx.x & 31, i0 = threadIdx.x >> 5;
  #pragma unroll
  for (int ii=0; ii<32; ii+=8){
    int r = r0+i0+ii, c = c0+j;
    u16 v = 0;
    if (r < R && c < C) v = f2bf(src[(long)r*C + c]);
    tile[i0+ii][j] = v;
  }
  __syncthreads();
  #pragma unroll
  for (int ii=0; ii<32; ii+=8){
    int c = c0+i0+ii, r = r0+j;
    if (c < C && r < Rpad) dst[(long)c*Rpad + r] = tile[j][i0+ii];
  }
}

// ---------------- G1+MLP fused: per block, 128 edge rows of one batch.
// Phase 1: edges_tile[128x256] = H_tile @ ori (acc in regs), emits HT.
//          A-path uses depth-2 register prefetch (paA/paB, static unroll x2).
// Phase 2: per type t, GEMM1(+relu+ed-scale)->Hs, GEMM2 transposed -> acc2 -> EFt.
//          Weights read DIRECTLY from global (L2-resident, 640KB total): no staging,
//          2 barriers per t instead of 14.
// LDS 109568 B: tables 10K | {As 16K | At 17K | Bs 32K} aliased by {Es 64K} | Hs 32K.
__global__ __launch_bounds__(512,2) void g1mlp_kernel(
    const float* __restrict__ Hm, const u16* __restrict__ oriT,
    const u16* __restrict__ W1T, const u16* __restrict__ W2T,
    const float* __restrict__ b1, const float* __restrict__ b2,
    const float* __restrict__ edist, u16* __restrict__ HT, u16* __restrict__ EFt){
  __shared__ __align__(16) char smem[109568];
  float* eds = (float*)(smem);            // 640 f   2560 B
  float* b1s = (float*)(smem + 2560);     // 640 f   2560 B
  float* b2s = (float*)(smem + 5120);     // 1280 f  5120 B
  u16*   As  = (u16*)(smem + 10240);      // [2][4096] 16384 B (phase 1)
  u16*   At  = (u16*)(smem + 26624);      // [2][4352] 17408 B (phase 1)
  u16*   Bs  = (u16*)(smem + 44032);      // [2][8192] 32768 B (phase 1 B staging)
  u16*   Es  = (u16*)(smem + 10240);      // [8][4096] 65536 B (phase 2; aliases As+At+Bs)
  u16*   Hs  = (u16*)(smem + 76800);      // [4][4096] 32768 B (phase 2)

  const int b = blockIdx.y, bm = blockIdx.x*128;
  const int tid = threadIdx.x;
  const int w = tid>>6, quad = (tid&63)>>4, l16 = tid&15;
  const int wm = (w&1)*64, wn = (w>>1)*64;      // phase1: 2M x 4N waves, 64x64 each
  const float* Ab = Hm + (size_t)b*8000*2000 + (size_t)bm*2000;
  const u16*  Bb = oriT + (size_t)b*256*2048;
  u16* HTb = HT + (size_t)b*2048*8000;
  const bool edge_blk = (bm == 7936);           // last M-block: rows 64..127 OOB

  // small tables (visible after first barrier; never rewritten)
  for (int i=tid;i<640;i+=512){
    int e = bm + i/5;
    eds[i] = (e < 8000) ? edist[((size_t)b*8000 + bm)*5 + i] : 0.f;
  }
  for (int i=tid;i<640;i+=512)  b1s[i] = b1[i];
  for (int i=tid;i<1280;i+=512) b2s[i] = b2[i];

  float4 paA[2], paB[2];
  auto loadA = [&](int kt, float4 (&p)[2], bool guard){
    const int k0 = kt*32;
    #pragma unroll
    for (int i=0;i<2;i++){
      int idx = i*512+tid, row = idx>>3, c4 = (idx&7)*4;
      if (!guard){
        p[i] = *(const float4*)(Ab + (size_t)row*2000 + k0+c4);
      } else {
        bool ok = (bm+row < 8000) && (k0+c4 < 2000);
        p[i] = ok ? *(const float4*)(Ab + (size_t)row*2000 + k0+c4) : make_float4(0.f,0.f,0.f,0.f);
      }
    }
  };
  auto storeA = [&](int kt, float4 (&p)[2]){
    const int buf = kt&1;
    #pragma unroll
    for (int i=0;i<2;i++){
      int idx = i*512+tid, row = idx>>3, c4 = (idx&7)*4;
      ushort4 o; o.x=f2bf(p[i].x); o.y=f2bf(p[i].y); o.z=f2bf(p[i].z); o.w=f2bf(p[i].w);
      *(ushort4*)(&As[buf*4096 + idx*4]) = o;
      At[buf*4352 + (c4+0)*136 + (row ^ ((((c4+0)>>3)&3)<<3))] = o.x;
      At[buf*4352 + (c4+1)*136 + (row ^ ((((c4+1)>>3)&3)<<3))] = o.y;
      At[buf*4352 + (c4+2)*136 + (row ^ ((((c4+2)>>3)&3)<<3))] = o.z;
      At[buf*4352 + (c4+3)*136 + (row ^ ((((c4+3)>>3)&3)<<3))] = o.w;
    }
  };
  auto stageB = [&](int kt){
    const int buf = kt&1, k0 = kt*32;
    #pragma unroll
    for (int i=0;i<2;i++){
      int idx = i*512+tid;
      int row = idx>>2, c8 = (idx&3)*8;
      GLL16(Bb + (size_t)row*2048 + k0+c8, &Bs[buf*8192 + (i*512 + w*64)*8]);
    }
  };
  auto htwrite = [&](int kt){
    const int buf = kt&1, k0 = kt*32;
    int kk = tid>>4, c = tid&15, m0 = c*8;
    if (bm + m0 < 8000){
      u16x8 v = *(const u16x8*)(&At[buf*4352 + kk*136 + (m0 ^ (((kk>>3)&3)<<3))]);
      *(u16x8*)(HTb + (size_t)(k0+kk)*8000 + bm + m0) = v;
    }
  };

  f32x4 acc[4][4];
  #pragma unroll
  for (int i=0;i<4;i++)
    #pragma unroll
    for (int j=0;j<4;j++) acc[i][j] = (f32x4){0.f,0.f,0.f,0.f};

  auto domfma = [&](int buf){
    bf16x8 af[4], bf[4];
    #pragma unroll
    for (int mi=0;mi<4;mi++) af[mi] = *(const bf16x8*)(&As[buf*4096 + (wm+mi*16+l16)*32 + quad*8]);
    #pragma unroll
    for (int ni=0;ni<4;ni++) bf[ni] = *(const bf16x8*)(&Bs[buf*8192 + (wn+ni*16+l16)*32 + quad*8]);
    #pragma unroll
    for (int mi=0;mi<4;mi++)
      #pragma unroll
      for (int ni=0;ni<4;ni++)
        acc[mi][ni] = __builtin_amdgcn_mfma_f32_16x16x32_bf16(af[mi], bf[ni], acc[mi][ni], 0,0,0);
  };

  loadA(0, paA, edge_blk); loadA(1, paB, edge_blk); stageB(0);
  for (int kt=0; kt<64; kt+=2){
    // even sub-iter (buffer 0)
    storeA(kt, paA);
    __syncthreads();
    if (kt+2 < 64) loadA(kt+2, paA, edge_blk || (kt+2 >= 62));
    stageB(kt+1);
    htwrite(kt);
    domfma(0);
    // odd sub-iter (buffer 1)
    storeA(kt+1, paB);
    __syncthreads();
    if (kt+3 < 64) loadA(kt+3, paB, edge_blk || (kt+3 >= 62));
    if (kt+2 < 64) stageB(kt+2);
    htwrite(kt+1);
    domfma(1);
  }

  // ---- phase transition: all waves done reading As/At/Bs
  __syncthreads();
  // edges tile -> Es[d>>5][m][d&31]
  #pragma unroll
  for (int mi=0;mi<4;mi++){
    #pragma unroll
    for (int r=0;r<4;r++){
      int m = wm + mi*16 + quad*4 + r;
      #pragma unroll
      for (int ni=0;ni<4;ni++){
        int d = wn + ni*16 + l16;
        Es[(d>>5)*4096 + m*32 + (d&31)] = f2bf(acc[mi][ni][r]);
      }
    }
  }
  __syncthreads();

  // ---- phase 2: per-type MLP; weights direct from global (L2-resident)
  const int wm1 = (w&1)*64, wh1 = ((w>>1)&3)*32;   // GEMM1: 128m x 128h
  const int wd2 = (w&3)*64, wm2 = (w>>2)*64;       // GEMM2: 256d x 128m

  f32x4 acc2[4][4];
  #pragma unroll
  for (int i=0;i<4;i++)
    #pragma unroll
    for (int j=0;j<4;j++) acc2[i][j] = (f32x4){0.f,0.f,0.f,0.f};

  for (int t=0;t<5;t++){
    f32x4 acc1[4][2];
    #pragma unroll
    for (int i=0;i<4;i++){ acc1[i][0] = (f32x4){0.f,0.f,0.f,0.f}; acc1[i][1] = (f32x4){0.f,0.f,0.f,0.f}; }
    // GEMM1: hidden = edges @ W1T[t]; A from LDS, B direct from global; NO barriers
    #pragma unroll
    for (int kt=0;kt<8;kt++){
      bf16x8 af[4], bfr[2];
      #pragma unroll
      for (int ni=0;ni<2;ni++)
        bfr[ni] = *(const bf16x8*)(W1T + ((size_t)t*128 + wh1+ni*16+l16)*256 + kt*32 + quad*8);
      #pragma unroll
      for (int mi=0;mi<4;mi++) af[mi] = *(const bf16x8*)(&Es[kt*4096 + (wm1+mi*16+l16)*32 + quad*8]);
      #pragma unroll
      for (int mi=0;mi<4;mi++)
        #pragma unroll
        for (int ni=0;ni<2;ni++)
          acc1[mi][ni] = __builtin_amdgcn_mfma_f32_16x16x32_bf16(af[mi], bfr[ni], acc1[mi][ni], 0,0,0);
    }
    __syncthreads();   // prev t's GEMM2 done reading Hs
    // epilogue1: relu + bias + ed-scale -> Hs
    #pragma unroll
    for (int mi=0;mi<4;mi++){
      #pragma unroll
      for (int r=0;r<4;r++){
        int lrow = wm1 + mi*16 + quad*4 + r;
        float s = eds[lrow*5 + t];
        #pragma unroll
        for (int ni=0;ni<2;ni++){
          int ch = wh1 + ni*16 + l16;
          float v = fmaxf(acc1[mi][ni][r] + b1s[t*128 + ch], 0.f) * s;
          Hs[(ch>>5)*4096 + lrow*32 + (ch&31)] = f2bf(v);
        }
      }
    }
    __syncthreads();   // Hs ready
    // GEMM2 (transposed): acc2[d][m] += W2T[t] x hidden; A direct global, B from LDS
    #pragma unroll
    for (int kk=0;kk<4;kk++){
      bf16x8 af2[4], bf2[4];
      #pragma unroll
      for (int mi=0;mi<4;mi++)
        af2[mi] = *(const bf16x8*)(W2T + ((size_t)t*256 + wd2+mi*16+l16)*128 + kk*32 + quad*8);
      #pragma unroll
      for (int ni=0;ni<4;ni++) bf2[ni] = *(const bf16x8*)(&Hs[kk*4096 + (wm2+ni*16+l16)*32 + quad*8]);
      #pragma unroll
      for (int mi=0;mi<4;mi++)
        #pragma unroll
        for (int ni=0;ni<4;ni++)
          acc2[mi][ni] = __builtin_amdgcn_mfma_f32_16x16x32_bf16(af2[mi], bf2[ni], acc2[mi][ni], 0,0,0);
    }
  }
  // epilogue2: add bias-dot, write EFt[b][d][e] directly
  #pragma unroll
  for (int mi=0;mi<4;mi++){
    #pragma unroll
    for (int r=0;r<4;r++){
      int d = wd2 + mi*16 + quad*4 + r;
      #pragma unroll
      for (int ni=0;ni<4;ni++){
        int mc = wm2 + ni*16 + l16;
        int e = bm + mc;
        if (e < 8000){
          float bias = eds[mc*5+0]*b2s[d] + eds[mc*5+1]*b2s[256+d] + eds[mc*5+2]*b2s[512+d]
                     + eds[mc*5+3]*b2s[768+d] + eds[mc*5+4]*b2s[1024+d];
          EFt[((size_t)b*256 + d)*8000 + e] = f2bf(acc2[mi][ni][r] + bias);
        }
      }
    }
  }
}

// ---------------- G3: part[ks][b,m,d] = sum_{e in slice} HT[b,m,e]*EFt[b,d,e]
// 1-D grid of 256, XCD-chunked swizzle: each XCD sees one b (EFt[b]=4MB fits its L2).
__global__ __launch_bounds__(512,2) void g3_kernel(
    const u16* __restrict__ HT, const u16* __restrict__ EFt, float* __restrict__ part){
  __shared__ u16 As[2][128*32];
  __shared__ u16 Bs[2][256*32];
  const int wg = ((int)blockIdx.x & 7)*32 + ((int)blockIdx.x >> 3);   // bijective, 256%8==0
  const int bm = (wg & 15)*128, ks = (wg>>4)&3, b = wg>>6;
  const int tid = threadIdx.x;
  const int w = tid>>6, quad = (tid&63)>>4, l16 = tid&15;
  const int wm = (w&1)*64, wn = (w>>1)*64;
  const u16* Ab = HT + (size_t)b*2048*8000 + (size_t)bm*8000;
  const u16* Bb = EFt + (size_t)b*256*8000;
  const int it0 = (250*ks)/4, it1 = (250*(ks+1))/4;

  auto stage = [&](int kt){
    const int buf = kt&1, k0 = kt*32;
    {
      int row = tid>>2, c8 = (tid&3)*8;
      GLL16(Ab + (size_t)row*8000 + k0+c8, &As[buf][(w*64)*8]);
    }
    #pragma unroll
    for (int i=0;i<2;i++){
      int idx = i*512+tid, row = idx>>2, c8 = (idx&3)*8;
      GLL16(Bb + (size_t)row*8000 + k0+c8, &Bs[buf][(i*512 + w*64)*8]);
    }
  };

  f32x4 acc[4][4];
  #pragma unroll
  for (int i=0;i<4;i++)
    #pragma unroll
    for (int j=0;j<4;j++) acc[i][j] = (f32x4){0.f,0.f,0.f,0.f};

  stage(it0);
  for (int kt=it0; kt<it1; kt++){
    __syncthreads();
    if (kt+1 < it1) stage(kt+1);
    const int buf = kt&1;
    bf16x8 af[4], bf[4];
    #pragma unroll
    for (int mi=0;mi<4;mi++) af[mi] = *(const bf16x8*)(&As[buf][(wm+mi*16+l16)*32 + quad*8]);
    #pragma unroll
    for (int ni=0;ni<4;ni++) bf[ni] = *(const bf16x8*)(&Bs[buf][(wn+ni*16+l16)*32 + quad*8]);
    #pragma unroll
    for (int mi=0;mi<4;mi++)
      #pragma unroll
      for (int ni=0;ni<4;ni++)
        acc[mi][ni] = __builtin_amdgcn_mfma_f32_16x16x32_bf16(af[mi], bf[ni], acc[mi][ni], 0,0,0);
  }
  float* dst0 = part + ((size_t)(b*4 + ks)*2048)*256;
  #pragma unroll
  for (int mi=0;mi<4;mi++){
    #pragma unroll
    for (int r=0;r<4;r++){
      int gm = bm + wm + mi*16 + quad*4 + r;
      float* dst = dst0 + (size_t)gm*256;
      #pragma unroll
      for (int ni=0;ni<4;ni++) dst[wn + ni*16 + l16] = acc[mi][ni][r];
    }
  }
}

// ---------------- assemble: out[b,n,:256] = sum_ks part ; out[b,n,256:] = ori[b,n,:]
__global__ void assemble_kernel(const float* __restrict__ part, const float* __restrict__ ori,
                                float* __restrict__ out){
  const int b = blockIdx.y;
  int u = blockIdx.x*256 + threadIdx.x;          // 500*256 = 128000 = 2000*64
  int n = u>>6, c4 = (u&63)*4;
  f32x4 s = (f32x4){0.f,0.f,0.f,0.f};
  #pragma unroll
  for (int ks=0; ks<4; ks++)
    s += *(const f32x4*)(part + ((size_t)(b*4+ks)*2048 + n)*256 + c4);
  float* dst = out + ((size_t)(b*2000+n))*512;
  *(f32x4*)(dst + c4) = s;
  *(f32x4*)(dst + 256 + c4) = *(const f32x4*)(ori + ((size_t)(b*2000+n))*256 + c4);
}

extern "C" void kernel_launch(void* const* d_in, const int* in_sizes, int n_in,
                              void* d_out, int out_size, void* d_ws, size_t ws_size,
                              hipStream_t stream) {
  const float* ed  = (const float*)d_in[0];   // [4,8000,5]
  const float* Hm  = (const float*)d_in[1];   // [4,8000,2000]
  const float* ori = (const float*)d_in[2];   // [4,2000,256]
  const float* W1  = (const float*)d_in[3];   // [5,256,128]
  const float* b1  = (const float*)d_in[4];   // [5,128]
  const float* W2  = (const float*)d_in[5];   // [5,128,256]
  const float* b2  = (const float*)d_in[6];   // [5,256]
  float* out = (float*)d_out;                 // [4,2000,512]
  char* ws = (char*)d_ws;

  u16* HT    = (u16*)(ws);                 // 4*2048*8000*2 = 131,072,000
  u16* oriT  = (u16*)(ws + 131072000);     // 4*256*2048*2  =   4,194,304
  u16* W1T   = (u16*)(ws + 135266304);     // 5*128*256*2   =     327,680
  u16* W2T   = (u16*)(ws + 135593984);     // 5*256*128*2   =     327,680
  u16* EFt   = (u16*)(ws + 152305664);     // 4*256*8000*2  =  16,384,000
  float* part = (float*)(ws + 168689664);  // 4*4*2048*256*4 = 33,554,432 (end ~202.2 MB)

  hipLaunchKernelGGL(transpose_f32, dim3(64,8,4), dim3(256), 0, stream,
                     ori, oriT, 2000, 256, 2048, 512000L, 524288L);
  hipLaunchKernelGGL(transpose_f32, dim3(8,4,5), dim3(256), 0, stream,
                     W1, W1T, 256, 128, 256, 32768L, 32768L);
  hipLaunchKernelGGL(transpose_f32, dim3(4,8,5), dim3(256), 0, stream,
                     W2, W2T, 128, 256, 128, 32768L, 32768L);

  hipLaunchKernelGGL(g1mlp_kernel, dim3(63,4), dim3(512), 0, stream,
                     Hm, oriT, W1T, W2T, b1, b2, ed, HT, EFt);
  hipLaunchKernelGGL(g3_kernel, dim3(256), dim3(512), 0, stream, HT, EFt, part);
  hipLaunchKernelGGL(assemble_kernel, dim3(500,4), dim3(256), 0, stream, part, ori, out);

  (void)in_sizes; (void)n_in; (void)ws_size;
}

// Round 7
// 529.086 us; speedup vs baseline: 1.0215x; 1.0215x over previous
//
#include <hip/hip_runtime.h>
#include <hip/hip_bf16.h>

typedef unsigned short u16;
typedef short bf16x8 __attribute__((ext_vector_type(8)));
typedef float f32x4 __attribute__((ext_vector_type(4)));
typedef unsigned short u16x8 __attribute__((ext_vector_type(8)));

#define GLL16(gp, lp) __builtin_amdgcn_global_load_lds( \
    (__attribute__((address_space(1))) const unsigned int*)(gp), \
    (__attribute__((address_space(3))) unsigned int*)(lp), 16, 0, 0)

// HW RNE f32->bf16 (compiler pairs these into v_cvt_pk_bf16_f32)
static __device__ __forceinline__ u16 f2bf(float f){
  return __builtin_bit_cast(u16, __float2bfloat16(f));
}

// ---------------- transpose + convert: dst[b][c][r] = bf16(src[b][r][c]), r zero-padded to Rpad
__global__ void transpose_f32(const float* __restrict__ src, u16* __restrict__ dst,
                              int R, int C, int Rpad, long sB, long dB){
  __shared__ u16 tile[32][33];
  const int b = blockIdx.z;
  src += (long)b*sB; dst += (long)b*dB;
  const int r0 = blockIdx.x*32, c0 = blockIdx.y*32;
  const int j = threadIdx.x & 31, i0 = threadIdx.x >> 5;
  #pragma unroll
  for (int ii=0; ii<32; ii+=8){
    int r = r0+i0+ii, c = c0+j;
    u16 v = 0;
    if (r < R && c < C) v = f2bf(src[(long)r*C + c]);
    tile[i0+ii][j] = v;
  }
  __syncthreads();
  #pragma unroll
  for (int ii=0; ii<32; ii+=8){
    int c = c0+i0+ii, r = r0+j;
    if (c < C && r < Rpad) dst[(long)c*Rpad + r] = tile[j][i0+ii];
  }
}

// ---------------- G1+MLP fused (R4 structure + bank-conflict slot-swizzle).
// All [row][32k] bf16 tiles store k-chunk k8 (16B) at slot k8 ^ (row&3).
// Reads use kx = (quad ^ (l16&3))*8 since fragment rows are == l16 (mod 4).
// GLL16-staged tiles keep linear LDS dest and pre-swizzle the GLOBAL source.
__global__ __launch_bounds__(512,2) void g1mlp_kernel(
    const float* __restrict__ Hm, const u16* __restrict__ oriT,
    const u16* __restrict__ W1T, const u16* __restrict__ W2T,
    const float* __restrict__ b1, const float* __restrict__ b2,
    const float* __restrict__ edist, u16* __restrict__ HT, u16* __restrict__ EFt){
  __shared__ __align__(16) char smem[141312];
  u16*   Bs  = (u16*)(smem);              // [2][8192]  32768 B (B/W staging)
  float* eds = (float*)(smem + 32768);    // 640 f
  float* b1s = (float*)(smem + 35328);    // 640 f
  float* b2s = (float*)(smem + 37888);    // 1280 f
  u16*   As  = (u16*)(smem + 43008);      // [2][4096]  (phase 1)
  u16*   At  = (u16*)(smem + 59392);      // [2][4352]  (phase 1)
  u16*   Es  = (u16*)(smem + 43008);      // [8][4096]  (phase 2, aliases As+At+free)
  u16*   Hs  = (u16*)(smem + 108544);     // [4][4096]  (phase 2)

  const int b = blockIdx.y, bm = blockIdx.x*128;
  const int tid = threadIdx.x;
  const int w = tid>>6, quad = (tid&63)>>4, l16 = tid&15;
  const int kx = (quad ^ (l16&3))*8;            // swizzled read slot (u16 units)
  const int wm = (w&1)*64, wn = (w>>1)*64;      // phase1: 2M x 4N waves, 64x64 each
  const float* Ab = Hm + (size_t)b*8000*2000 + (size_t)bm*2000;
  const u16*  Bb = oriT + (size_t)b*256*2048;
  u16* HTb = HT + (size_t)b*2048*8000;
  const bool edge_blk = (bm == 7936);           // last M-block: rows 64..127 OOB

  for (int i=tid;i<640;i+=512){
    int e = bm + i/5;
    eds[i] = (e < 8000) ? edist[((size_t)b*8000 + bm)*5 + i] : 0.f;
  }
  for (int i=tid;i<640;i+=512)  b1s[i] = b1[i];
  for (int i=tid;i<1280;i+=512) b2s[i] = b2[i];

  float4 pa[2];
  auto loadA = [&](int kt, bool guard){
    const int k0 = kt*32;
    #pragma unroll
    for (int i=0;i<2;i++){
      int idx = i*512+tid, row = idx>>3, c4 = (idx&7)*4;
      if (!guard){
        pa[i] = *(const float4*)(Ab + (size_t)row*2000 + k0+c4);
      } else {
        bool ok = (bm+row < 8000) && (k0+c4 < 2000);
        pa[i] = ok ? *(const float4*)(Ab + (size_t)row*2000 + k0+c4) : make_float4(0.f,0.f,0.f,0.f);
      }
    }
  };
  auto storeA = [&](int kt){
    const int buf = kt&1;
    #pragma unroll
    for (int i=0;i<2;i++){
      int idx = i*512+tid, row = idx>>3, c4 = (idx&7)*4;
      ushort4 o; o.x=f2bf(pa[i].x); o.y=f2bf(pa[i].y); o.z=f2bf(pa[i].z); o.w=f2bf(pa[i].w);
      // As: slot-swizzled write (ushort4 = half a 16B slot, stays in-slot)
      int sl = (((c4>>3) ^ row) & 3)*8 + (c4&7);
      *(ushort4*)(&As[buf*4096 + row*32 + sl]) = o;
      At[buf*4352 + (c4+0)*136 + (row ^ ((((c4+0)>>3)&3)<<3))] = o.x;
      At[buf*4352 + (c4+1)*136 + (row ^ ((((c4+1)>>3)&3)<<3))] = o.y;
      At[buf*4352 + (c4+2)*136 + (row ^ ((((c4+2)>>3)&3)<<3))] = o.z;
      At[buf*4352 + (c4+3)*136 + (row ^ ((((c4+3)>>3)&3)<<3))] = o.w;
    }
  };
  auto stageB = [&](int kt){
    const int buf = kt&1, k0 = kt*32;
    #pragma unroll
    for (int i=0;i<2;i++){
      int idx = i*512+tid;
      int row = idx>>2, c8s = (((idx&3) ^ (idx>>2)) & 3)*8;   // pre-swizzled source slot
      GLL16(Bb + (size_t)row*2048 + k0+c8s, &Bs[buf*8192 + (i*512 + w*64)*8]);
    }
  };
  auto htwrite = [&](int kt){
    const int buf = kt&1, k0 = kt*32;
    int kk = tid>>4, c = tid&15, m0 = c*8;
    if (bm + m0 < 8000){
      u16x8 v = *(const u16x8*)(&At[buf*4352 + kk*136 + (m0 ^ (((kk>>3)&3)<<3))]);
      *(u16x8*)(HTb + (size_t)(k0+kk)*8000 + bm + m0) = v;
    }
  };

  f32x4 acc[4][4];
  #pragma unroll
  for (int i=0;i<4;i++)
    #pragma unroll
    for (int j=0;j<4;j++) acc[i][j] = (f32x4){0.f,0.f,0.f,0.f};

  auto domfma = [&](int buf){
    bf16x8 af[4], bf[4];
    #pragma unroll
    for (int mi=0;mi<4;mi++) af[mi] = *(const bf16x8*)(&As[buf*4096 + (wm+mi*16+l16)*32 + kx]);
    #pragma unroll
    for (int ni=0;ni<4;ni++) bf[ni] = *(const bf16x8*)(&Bs[buf*8192 + (wn+ni*16+l16)*32 + kx]);
    #pragma unroll
    for (int mi=0;mi<4;mi++)
      #pragma unroll
      for (int ni=0;ni<4;ni++)
        acc[mi][ni] = __builtin_amdgcn_mfma_f32_16x16x32_bf16(af[mi], bf[ni], acc[mi][ni], 0,0,0);
  };

  loadA(0, edge_blk); stageB(0);
  for (int kt=0; kt<64; kt++){
    storeA(kt);
    __syncthreads();
    if (kt+1 < 64){ loadA(kt+1, edge_blk || (kt+1 >= 62)); stageB(kt+1); }
    htwrite(kt);
    domfma(kt&1);
  }

  // ---- phase transition
  __syncthreads();
  // pre-stage W1(t=0,kt=0) into Bs buf0 (pre-swizzled source)
  {
    int row = tid>>2, c8s = (((tid&3) ^ (tid>>2)) & 3)*8;
    GLL16(W1T + (size_t)row*256 + c8s, &Bs[0*8192 + (w*64)*8]);
  }
  // edges tile -> Es (slot-swizzled scalar writes)
  #pragma unroll
  for (int mi=0;mi<4;mi++){
    #pragma unroll
    for (int r=0;r<4;r++){
      int m = wm + mi*16 + quad*4 + r;
      #pragma unroll
      for (int ni=0;ni<4;ni++){
        int d = wn + ni*16 + l16;
        Es[(d>>5)*4096 + m*32 + ((((d>>3) ^ m)&3)*8) + (d&7)] = f2bf(acc[mi][ni][r]);
      }
    }
  }

  // ---- phase 2: per-type MLP, staged weights (double-buffered Bs)
  const int wm1 = (w&1)*64, wh1 = ((w>>1)&3)*32;   // GEMM1: 128m x 128h
  const int wd2 = (w&3)*64, wm2 = (w>>2)*64;       // GEMM2: 256d x 128m

  auto stageW1 = [&](int t, int kt){   // [128h][32k] 8KB
    const int buf = kt&1;
    int row = tid>>2, c8s = (((tid&3) ^ (tid>>2)) & 3)*8;
    GLL16(W1T + ((size_t)t*128 + row)*256 + kt*32 + c8s, &Bs[buf*8192 + (w*64)*8]);
  };
  auto stageW2 = [&](int t, int kk){   // [256d][32k] 16KB
    const int buf = kk&1;
    #pragma unroll
    for (int i=0;i<2;i++){
      int idx = i*512+tid, row = idx>>2, c8s = (((idx&3) ^ (idx>>2)) & 3)*8;
      GLL16(W2T + ((size_t)t*256 + row)*128 + kk*32 + c8s, &Bs[buf*8192 + (i*512 + w*64)*8]);
    }
  };

  f32x4 acc2[4][4];
  #pragma unroll
  for (int i=0;i<4;i++)
    #pragma unroll
    for (int j=0;j<4;j++) acc2[i][j] = (f32x4){0.f,0.f,0.f,0.f};

  for (int t=0;t<5;t++){
    f32x4 acc1[4][2];
    #pragma unroll
    for (int i=0;i<4;i++){ acc1[i][0] = (f32x4){0.f,0.f,0.f,0.f}; acc1[i][1] = (f32x4){0.f,0.f,0.f,0.f}; }
    // GEMM1: hidden = edges @ W1T[t]
    for (int kt=0;kt<8;kt++){
      __syncthreads();                       // buf kt&1 ready; buf^1 free to overwrite
      if (kt<7) stageW1(t,kt+1); else stageW2(t,0);
      const int buf = kt&1;
      bf16x8 af[4], bfr[2];
      #pragma unroll
      for (int mi=0;mi<4;mi++) af[mi] = *(const bf16x8*)(&Es[kt*4096 + (wm1+mi*16+l16)*32 + kx]);
      #pragma unroll
      for (int ni=0;ni<2;ni++) bfr[ni] = *(const bf16x8*)(&Bs[buf*8192 + (wh1+ni*16+l16)*32 + kx]);
      #pragma unroll
      for (int mi=0;mi<4;mi++)
        #pragma unroll
        for (int ni=0;ni<2;ni++)
          acc1[mi][ni] = __builtin_amdgcn_mfma_f32_16x16x32_bf16(af[mi], bfr[ni], acc1[mi][ni], 0,0,0);
    }
    __syncthreads();     // prev reads of Hs (t-1 GEMM2) are long done; sync before rewrite
    // epilogue1: relu + bias + ed-scale -> Hs (slot-swizzled)
    #pragma unroll
    for (int mi=0;mi<4;mi++){
      #pragma unroll
      for (int r=0;r<4;r++){
        int lrow = wm1 + mi*16 + quad*4 + r;
        float s = eds[lrow*5 + t];
        #pragma unroll
        for (int ni=0;ni<2;ni++){
          int ch = wh1 + ni*16 + l16;
          float v = fmaxf(acc1[mi][ni][r] + b1s[t*128 + ch], 0.f) * s;
          Hs[(ch>>5)*4096 + lrow*32 + ((((ch>>3) ^ lrow)&3)*8) + (ch&7)] = f2bf(v);
        }
      }
    }
    // GEMM2 (transposed): acc2[d][m] += W2T[t] x hidden
    for (int kk=0;kk<4;kk++){
      __syncthreads();                       // Hs visible (kk=0) / buf kk&1 ready
      if (kk<3) stageW2(t,kk+1); else if (t<4) stageW1(t+1,0);
      const int buf = kk&1;
      bf16x8 af2[4], bf2[4];
      #pragma unroll
      for (int mi=0;mi<4;mi++) af2[mi] = *(const bf16x8*)(&Bs[buf*8192 + (wd2+mi*16+l16)*32 + kx]);
      #pragma unroll
      for (int ni=0;ni<4;ni++) bf2[ni] = *(const bf16x8*)(&Hs[kk*4096 + (wm2+ni*16+l16)*32 + kx]);
      #pragma unroll
      for (int mi=0;mi<4;mi++)
        #pragma unroll
        for (int ni=0;ni<4;ni++)
          acc2[mi][ni] = __builtin_amdgcn_mfma_f32_16x16x32_bf16(af2[mi], bf2[ni], acc2[mi][ni], 0,0,0);
    }
  }
  // epilogue2: add bias-dot, write EFt[b][d][e] directly
  #pragma unroll
  for (int mi=0;mi<4;mi++){
    #pragma unroll
    for (int r=0;r<4;r++){
      int d = wd2 + mi*16 + quad*4 + r;
      #pragma unroll
      for (int ni=0;ni<4;ni++){
        int mc = wm2 + ni*16 + l16;
        int e = bm + mc;
        if (e < 8000){
          float bias = eds[mc*5+0]*b2s[d] + eds[mc*5+1]*b2s[256+d] + eds[mc*5+2]*b2s[512+d]
                     + eds[mc*5+3]*b2s[768+d] + eds[mc*5+4]*b2s[1024+d];
          EFt[((size_t)b*256 + d)*8000 + e] = f2bf(acc2[mi][ni][r] + bias);
        }
      }
    }
  }
}

// ---------------- G3: part[ks][b,m,d] = sum_{e in slice} HT[b,m,e]*EFt[b,d,e]
// XCD-chunked swizzle; slot-swizzled LDS tiles (pre-swizzled GLL16 sources).
__global__ __launch_bounds__(512,2) void g3_kernel(
    const u16* __restrict__ HT, const u16* __restrict__ EFt, float* __restrict__ part){
  __shared__ u16 As[2][128*32];
  __shared__ u16 Bs[2][256*32];
  const int wg = ((int)blockIdx.x & 7)*32 + ((int)blockIdx.x >> 3);   // bijective, 256%8==0
  const int bm = (wg & 15)*128, ks = (wg>>4)&3, b = wg>>6;
  const int tid = threadIdx.x;
  const int w = tid>>6, quad = (tid&63)>>4, l16 = tid&15;
  const int kx = (quad ^ (l16&3))*8;
  const int wm = (w&1)*64, wn = (w>>1)*64;
  const u16* Ab = HT + (size_t)b*2048*8000 + (size_t)bm*8000;
  const u16* Bb = EFt + (size_t)b*256*8000;
  const int it0 = (250*ks)/4, it1 = (250*(ks+1))/4;

  auto stage = [&](int kt){
    const int buf = kt&1, k0 = kt*32;
    {
      int row = tid>>2, c8s = (((tid&3) ^ (tid>>2)) & 3)*8;
      GLL16(Ab + (size_t)row*8000 + k0+c8s, &As[buf][(w*64)*8]);
    }
    #pragma unroll
    for (int i=0;i<2;i++){
      int idx = i*512+tid, row = idx>>2, c8s = (((idx&3) ^ (idx>>2)) & 3)*8;
      GLL16(Bb + (size_t)row*8000 + k0+c8s, &Bs[buf][(i*512 + w*64)*8]);
    }
  };

  f32x4 acc[4][4];
  #pragma unroll
  for (int i=0;i<4;i++)
    #pragma unroll
    for (int j=0;j<4;j++) acc[i][j] = (f32x4){0.f,0.f,0.f,0.f};

  stage(it0);
  for (int kt=it0; kt<it1; kt++){
    __syncthreads();
    if (kt+1 < it1) stage(kt+1);
    const int buf = kt&1;
    bf16x8 af[4], bf[4];
    #pragma unroll
    for (int mi=0;mi<4;mi++) af[mi] = *(const bf16x8*)(&As[buf][(wm+mi*16+l16)*32 + kx]);
    #pragma unroll
    for (int ni=0;ni<4;ni++) bf[ni] = *(const bf16x8*)(&Bs[buf][(wn+ni*16+l16)*32 + kx]);
    #pragma unroll
    for (int mi=0;mi<4;mi++)
      #pragma unroll
      for (int ni=0;ni<4;ni++)
        acc[mi][ni] = __builtin_amdgcn_mfma_f32_16x16x32_bf16(af[mi], bf[ni], acc[mi][ni], 0,0,0);
  }
  float* dst0 = part + ((size_t)(b*4 + ks)*2048)*256;
  #pragma unroll
  for (int mi=0;mi<4;mi++){
    #pragma unroll
    for (int r=0;r<4;r++){
      int gm = bm + wm + mi*16 + quad*4 + r;
      float* dst = dst0 + (size_t)gm*256;
      #pragma unroll
      for (int ni=0;ni<4;ni++) dst[wn + ni*16 + l16] = acc[mi][ni][r];
    }
  }
}

// ---------------- assemble: out[b,n,:256] = sum_ks part ; out[b,n,256:] = ori[b,n,:]
__global__ void assemble_kernel(const float* __restrict__ part, const float* __restrict__ ori,
                                float* __restrict__ out){
  const int b = blockIdx.y;
  int u = blockIdx.x*256 + threadIdx.x;          // 500*256 = 128000 = 2000*64
  int n = u>>6, c4 = (u&63)*4;
  f32x4 s = (f32x4){0.f,0.f,0.f,0.f};
  #pragma unroll
  for (int ks=0; ks<4; ks++)
    s += *(const f32x4*)(part + ((size_t)(b*4+ks)*2048 + n)*256 + c4);
  float* dst = out + ((size_t)(b*2000+n))*512;
  *(f32x4*)(dst + c4) = s;
  *(f32x4*)(dst + 256 + c4) = *(const f32x4*)(ori + ((size_t)(b*2000+n))*256 + c4);
}

extern "C" void kernel_launch(void* const* d_in, const int* in_sizes, int n_in,
                              void* d_out, int out_size, void* d_ws, size_t ws_size,
                              hipStream_t stream) {
  const float* ed  = (const float*)d_in[0];   // [4,8000,5]
  const float* Hm  = (const float*)d_in[1];   // [4,8000,2000]
  const float* ori = (const float*)d_in[2];   // [4,2000,256]
  const float* W1  = (const float*)d_in[3];   // [5,256,128]
  const float* b1  = (const float*)d_in[4];   // [5,128]
  const float* W2  = (const float*)d_in[5];   // [5,128,256]
  const float* b2  = (const float*)d_in[6];   // [5,256]
  float* out = (float*)d_out;                 // [4,2000,512]
  char* ws = (char*)d_ws;

  u16* HT    = (u16*)(ws);                 // 4*2048*8000*2 = 131,072,000
  u16* oriT  = (u16*)(ws + 131072000);     // 4*256*2048*2  =   4,194,304
  u16* W1T   = (u16*)(ws + 135266304);     // 5*128*256*2   =     327,680
  u16* W2T   = (u16*)(ws + 135593984);     // 5*256*128*2   =     327,680
  u16* EFt   = (u16*)(ws + 152305664);     // 4*256*8000*2  =  16,384,000
  float* part = (float*)(ws + 168689664);  // 4*4*2048*256*4 = 33,554,432 (end ~202.2 MB)

  hipLaunchKernelGGL(transpose_f32, dim3(64,8,4), dim3(256), 0, stream,
                     ori, oriT, 2000, 256, 2048, 512000L, 524288L);
  hipLaunchKernelGGL(transpose_f32, dim3(8,4,5), dim3(256), 0, stream,
                     W1, W1T, 256, 128, 256, 32768L, 32768L);
  hipLaunchKernelGGL(transpose_f32, dim3(4,8,5), dim3(256), 0, stream,
                     W2, W2T, 128, 256, 128, 32768L, 32768L);

  hipLaunchKernelGGL(g1mlp_kernel, dim3(63,4), dim3(512), 0, stream,
                     Hm, oriT, W1T, W2T, b1, b2, ed, HT, EFt);
  hipLaunchKernelGGL(g3_kernel, dim3(256), dim3(512), 0, stream, HT, EFt, part);
  hipLaunchKernelGGL(assemble_kernel, dim3(500,4), dim3(256), 0, stream, part, ori, out);

  (void)in_sizes; (void)n_in; (void)ws_size;
}